// Round 12
// baseline (45609.894 us; speedup 1.0000x reference)
//
#include <hip/hip_runtime.h>
#include <stdint.h>

#define S_LEN 8192
#define E_DIM 100          // !!! actual embedding dim — R1-R11 fatally used 768
#define H_DIM 768
#define NTAG 7
#define G4 3072            // 4*H
#define NCHUNK 128

typedef unsigned short u16;

// tiny static: input dtype flag written by detect(), read by all kernels
__device__ int g_isbf16;

__device__ __forceinline__ u16 f2bf(float f) {
    union { float f; unsigned u; } v; v.f = f;
    unsigned b = v.u;
    unsigned r = (b + 0x7FFFu + ((b >> 16) & 1u)) >> 16;   // RN
    return (u16)r;
}
__device__ __forceinline__ float bf2f(u16 u) {
    union { unsigned u; float f; } v; v.u = ((unsigned)u) << 16;
    return v.f;
}
__device__ __forceinline__ float getv(const void* p, size_t i, int isbf) {
    return isbf ? bf2f(((const u16*)p)[i]) : ((const float*)p)[i];
}
__device__ __forceinline__ float sigm(float x) { return 1.0f / (1.0f + __expf(-x)); }

// ---------------------------------------------------------------------------
// Dtype probe (256 B read — safe under either dtype): bf16 N(0,1) data has a
// plausible exponent in ~100% of u16s; fp32 data's even u16s are mantissa
// noise (~9% plausible). 128 samples, threshold 100.
// ---------------------------------------------------------------------------
__global__ void detect(const void* x) {
    __shared__ int cnt;
    if (threadIdx.x == 0) cnt = 0;
    __syncthreads();
    unsigned v = ((const u16*)x)[2 * threadIdx.x];
    int e = (v >> 7) & 0xFF;
    if (e >= 110 && e <= 132) atomicAdd(&cnt, 1);
    __syncthreads();
    if (threadIdx.x == 0) g_isbf16 = (cnt >= 100) ? 1 : 0;
}

// ---------------------------------------------------------------------------
// Prep: fold biases -> fp32, seed h row 0 (bf16), c0 -> fp32.
// ---------------------------------------------------------------------------
__global__ void prep(const void* bihf, const void* bhhf,
                     const void* bihb, const void* bhhb,
                     const void* h0, const void* c0,
                     u16* __restrict__ hf, u16* __restrict__ hb,
                     float* __restrict__ cst, float* __restrict__ bias) {
    const int isbf = g_isbf16;
    int i = blockIdx.x * blockDim.x + threadIdx.x;   // 0..3071
    if (i < G4) {
        bias[i]      = getv(bihf, i, isbf) + getv(bhhf, i, isbf);
        bias[G4 + i] = getv(bihb, i, isbf) + getv(bhhb, i, isbf);
    }
    if (i < H_DIM) {
        hf[i] = f2bf(getv(h0, i, isbf));
        hb[i] = f2bf(getv(h0, H_DIM + i, isbf));
    }
    if (i < 2 * H_DIM) cst[i] = getv(c0, i, isbf);
}

// ---------------------------------------------------------------------------
// One LSTM timestep, both directions. 384 blocks x 256 thr; wave owns one
// hidden unit u: 4 gate dots = W_hh[g*768+u]·h_{t-1} (len 768) +
// W_ih[g*768+u]·x_t (len 100, on the fly). Kernel boundary = device barrier.
// ---------------------------------------------------------------------------
__global__ __launch_bounds__(256) void lstm_step(const void* x,
                                                 const void* wihf, const void* whhf,
                                                 const void* wihb, const void* whhb,
                                                 u16* __restrict__ hfseq,
                                                 u16* __restrict__ hbseq,
                                                 float* __restrict__ cstate,
                                                 const float* __restrict__ biasv,
                                                 int t) {
    const int isbf = g_isbf16;
    const int b = blockIdx.x;
    const int dir = (b >= 192) ? 1 : 0;
    const int wave = threadIdx.x >> 6, lane = threadIdx.x & 63;
    const int u = (b - dir * 192) * 4 + wave;        // 0..767
    u16* hseq = dir ? hbseq : hfseq;
    const void* Wih = dir ? wihb : wihf;
    const void* Whh = dir ? whhb : whhf;
    const int sx = dir ? (S_LEN - 1 - t) : t;

    float dot[4];
    if (isbf) {
        // h_{t-1} (our bf16 history): dword d = elems {2d,2d+1}; lane+64*i, i<6
        const unsigned* h32 = (const unsigned*)(hseq + (size_t)t * H_DIM);
        float hlo[6], hhi[6];
        #pragma unroll
        for (int i = 0; i < 6; ++i) {
            unsigned p = h32[lane + 64 * i];
            hlo[i] = bf2f((u16)p); hhi[i] = bf2f((u16)(p >> 16));
        }
        // x_t: 100 bf16 = 50 dwords (row byte offset sx*200, dword-aligned)
        const unsigned* x32 = (const unsigned*)((const u16*)x + (size_t)sx * E_DIM);
        float xlo = 0.f, xhi = 0.f;
        if (lane < 50) {
            unsigned q = x32[lane];
            xlo = bf2f((u16)q); xhi = bf2f((u16)(q >> 16));
        }
        #pragma unroll
        for (int g = 0; g < 4; ++g) {
            const unsigned* wh32 = (const unsigned*)((const u16*)Whh + (size_t)(g * H_DIM + u) * H_DIM);
            float a0 = 0.f, a1 = 0.f;
            #pragma unroll
            for (int i = 0; i < 6; ++i) {
                unsigned p = wh32[lane + 64 * i];
                a0 += bf2f((u16)p) * hlo[i];
                a1 += bf2f((u16)(p >> 16)) * hhi[i];
            }
            if (lane < 50) {
                const unsigned* wx32 = (const unsigned*)((const u16*)Wih + (size_t)(g * H_DIM + u) * E_DIM);
                unsigned q = wx32[lane];
                a0 += bf2f((u16)q) * xlo;
                a1 += bf2f((u16)(q >> 16)) * xhi;
            }
            dot[g] = a0 + a1;
        }
    } else {
        const u16* hrow = hseq + (size_t)t * H_DIM;
        float hv[12];
        #pragma unroll
        for (int i = 0; i < 12; ++i) hv[i] = bf2f(hrow[lane + 64 * i]);
        const float* xr = (const float*)x + (size_t)sx * E_DIM;
        float xv0 = xr[lane];                          // lane < 64 < 100: in-bounds
        float xv1 = (lane < 36) ? xr[lane + 64] : 0.f; // covers 64..99
        #pragma unroll
        for (int g = 0; g < 4; ++g) {
            const float* whf = (const float*)Whh + (size_t)(g * H_DIM + u) * H_DIM;
            const float* wxf = (const float*)Wih + (size_t)(g * H_DIM + u) * E_DIM;
            float a0 = 0.f;
            #pragma unroll
            for (int i = 0; i < 12; ++i) a0 += whf[lane + 64 * i] * hv[i];
            a0 += wxf[lane] * xv0;
            if (lane < 36) a0 += wxf[lane + 64] * xv1;
            dot[g] = a0;
        }
    }
    #pragma unroll
    for (int g = 0; g < 4; ++g)
        #pragma unroll
        for (int m = 1; m < 64; m <<= 1) dot[g] += __shfl_xor(dot[g], m);

    if (lane == 0) {
        const float* bias = biasv + dir * G4;
        float c = cstate[dir * H_DIM + u];
        float ii = sigm(dot[0] + bias[0 * H_DIM + u]);
        float ff = sigm(dot[1] + bias[1 * H_DIM + u]);
        float gg = tanhf(dot[2] + bias[2 * H_DIM + u]);
        float oo = sigm(dot[3] + bias[3 * H_DIM + u]);
        c = ff * c + ii * gg;
        cstate[dir * H_DIM + u] = c;
        hseq[(size_t)(t + 1) * H_DIM + u] = f2bf(oo * tanhf(c));
    }
}

// ---------------------------------------------------------------------------
// feats[s][j] = [hf[s], hb[s]] . w_tag[j] + b_tag[j]; one wave per s.
// ---------------------------------------------------------------------------
__global__ __launch_bounds__(256) void feats_kernel(const u16* __restrict__ hfseq,
                                                    const u16* __restrict__ hbseq,
                                                    const void* w_tag, const void* b_tag,
                                                    float* __restrict__ feats) {
    const int isbf = g_isbf16;
    const int wave = threadIdx.x >> 6, lane = threadIdx.x & 63;
    const int s = blockIdx.x * 4 + wave;
    if (s >= S_LEN) return;
    const u16* hf = hfseq + (size_t)(s + 1) * H_DIM;
    const u16* hb = hbseq + (size_t)(S_LEN - s) * H_DIM;
    float hv[12], hbv[12];
    #pragma unroll
    for (int i = 0; i < 12; ++i) {
        hv[i]  = bf2f(hf[lane + 64 * i]);
        hbv[i] = bf2f(hb[lane + 64 * i]);
    }
    float myf = 0.f;
    for (int j = 0; j < NTAG; ++j) {
        const size_t wr = (size_t)j * (2 * H_DIM);
        float d = 0.f;
        #pragma unroll
        for (int i = 0; i < 12; ++i)
            d += hv[i] * getv(w_tag, wr + lane + 64 * i, isbf)
               + hbv[i] * getv(w_tag, wr + H_DIM + lane + 64 * i, isbf);
        #pragma unroll
        for (int m = 1; m < 64; m <<= 1) d += __shfl_xor(d, m);
        if (lane == j) myf = d + getv(b_tag, j, isbf);
    }
    if (lane < NTAG) feats[(size_t)s * NTAG + lane] = myf;
}

// ---------------------------------------------------------------------------
// CRF parallel scan (log-semiring 7x7 product is associative).
// ---------------------------------------------------------------------------
__global__ void crf_chunks(const void* trans,
                           const float* __restrict__ feats,
                           float* __restrict__ cmats) {
    const int isbf = g_isbf16;
    const int c = blockIdx.x;
    const int lane = threadIdx.x;
    const bool act = lane < 49;
    const int i = act ? (lane / 7) : 0;
    const int j = lane % 7;
    float tc[7];
    #pragma unroll
    for (int k = 0; k < 7; ++k) tc[k] = getv(trans, k * 7 + j, isbf);
    float R = (act && (lane / 7) == j) ? 0.f : -1e30f;
    int s0 = 1 + c * 64;
    int s1 = s0 + 64; if (s1 > S_LEN) s1 = S_LEN;
    for (int t = s0; t < s1; ++t) {
        float fj = feats[t * NTAG + j];
        float r[7];
        #pragma unroll
        for (int k = 0; k < 7; ++k) r[k] = __shfl(R, i * 7 + k) + tc[k];
        float m = r[0];
        #pragma unroll
        for (int k = 1; k < 7; ++k) m = fmaxf(m, r[k]);
        float sum = 0.f;
        #pragma unroll
        for (int k = 0; k < 7; ++k) sum += __expf(r[k] - m);
        R = m + __logf(sum) + fj;
    }
    if (act) cmats[c * 49 + lane] = R;
}

__global__ void crf_final(const void* start_t, const void* end_t,
                          const float* __restrict__ feats,
                          const float* __restrict__ cmats,
                          void* __restrict__ out) {
    const int isbf = g_isbf16;
    const int lane = threadIdx.x;
    const int j = (lane < 7) ? lane : 0;
    float alpha = (lane < 7) ? (getv(start_t, lane, isbf) + feats[lane]) : -1e30f;
    for (int c = 0; c < NCHUNK; ++c) {
        float r[7];
        #pragma unroll
        for (int i = 0; i < 7; ++i)
            r[i] = __shfl(alpha, i) + cmats[c * 49 + i * 7 + j];
        float m = r[0];
        #pragma unroll
        for (int i = 1; i < 7; ++i) m = fmaxf(m, r[i]);
        float sum = 0.f;
        #pragma unroll
        for (int i = 0; i < 7; ++i) sum += __expf(r[i] - m);
        float na = m + __logf(sum);
        alpha = (lane < 7) ? na : -1e30f;
    }
    float v = (lane < 7) ? (alpha + getv(end_t, lane, isbf)) : -1e30f;
    float m = v;
    #pragma unroll
    for (int d = 1; d < 8; d <<= 1) m = fmaxf(m, __shfl_xor(m, d));
    float s = __expf(v - m);
    #pragma unroll
    for (int d = 1; d < 8; d <<= 1) s += __shfl_xor(s, d);
    if (lane == 0) {
        float r = m + __logf(s);
        if (isbf) ((u16*)out)[0] = f2bf(r);
        else      ((float*)out)[0] = r;
    }
}

// ---------------------------------------------------------------------------
extern "C" void kernel_launch(void* const* d_in, const int* in_sizes, int n_in,
                              void* d_out, int out_size, void* d_ws, size_t ws_size,
                              hipStream_t stream) {
    const void* sentence = d_in[0];      // (8192, 1, 100)
    const void* w_ih_f   = d_in[1];      // (3072, 100)
    const void* w_hh_f   = d_in[2];      // (3072, 768)
    const void* b_ih_f   = d_in[3];
    const void* b_hh_f   = d_in[4];
    const void* w_ih_b   = d_in[5];
    const void* w_hh_b   = d_in[6];
    const void* b_ih_b   = d_in[7];
    const void* b_hh_b   = d_in[8];
    const void* h0       = d_in[9];      // (2,1,768)
    const void* c0       = d_in[10];
    const void* w_tag    = d_in[11];     // (7, 1536)
    const void* b_tag    = d_in[12];
    const void* trans    = d_in[13];     // (7,7)
    const void* start_t  = d_in[14];
    const void* end_t    = d_in[15];
    (void)in_sizes; (void)n_in; (void)out_size; (void)ws_size;

    // ---- d_ws scratch: 25.5 MB, every byte rewritten each call ----
    char* ws = (char*)d_ws;
    size_t o = 0;
    auto take = [&](size_t bytes) -> char* {
        char* p = ws + o;
        o += (bytes + 255) & ~(size_t)255;
        return p;
    };
    u16*   hfseq  = (u16*)take((size_t)(S_LEN + 1) * H_DIM * 2);   // 12.58 MB
    u16*   hbseq  = (u16*)take((size_t)(S_LEN + 1) * H_DIM * 2);   // 12.58 MB
    float* cstate = (float*)take((size_t)2 * H_DIM * 4);
    float* biasv  = (float*)take((size_t)2 * G4 * 4);
    float* featsb = (float*)take((size_t)S_LEN * NTAG * 4);
    float* cmats  = (float*)take((size_t)NCHUNK * 49 * 4);

    detect<<<1, 128, 0, stream>>>(sentence);
    prep<<<12, 256, 0, stream>>>(b_ih_f, b_hh_f, b_ih_b, b_hh_b, h0, c0,
                                 hfseq, hbseq, cstate, biasv);

    for (int t = 0; t < S_LEN; ++t)
        lstm_step<<<384, 256, 0, stream>>>(sentence, w_ih_f, w_hh_f,
                                           w_ih_b, w_hh_b,
                                           hfseq, hbseq, cstate, biasv, t);

    feats_kernel<<<S_LEN / 4, 256, 0, stream>>>(hfseq, hbseq, w_tag, b_tag, featsb);
    crf_chunks<<<NCHUNK, 64, 0, stream>>>(trans, featsb, cmats);
    crf_final<<<1, 64, 0, stream>>>(start_t, end_t, featsb, cmats, d_out);
}